// Round 8
// baseline (349.839 us; speedup 1.0000x reference)
//
#include <hip/hip_runtime.h>

#define HW 3600
#define PADR 3712            // 29*128 padded rows
#define NF4 900
#define SLICE 2048           // cand entries per (batch, tile)
#define KSEL 100
#define NT 58                // 64-col tiles
typedef unsigned long long U64;

using short8   = __attribute__((ext_vector_type(8))) short;
using float4v  = __attribute__((ext_vector_type(4))) float;
using float16v = __attribute__((ext_vector_type(16))) float;

__device__ __forceinline__ unsigned monof(float f) {
    unsigned b = __float_as_uint(f);
    return (b & 0x80000000u) ? ~b : (b | 0x80000000u);
}
__device__ __forceinline__ float unmonof(unsigned m) {
    return __uint_as_float((m & 0x80000000u) ? (m ^ 0x80000000u) : ~m);
}
__device__ __forceinline__ unsigned short f2bf(float f) {   // RNE
    unsigned b = __float_as_uint(f);
    return (unsigned short)((b + 0x7FFFu + ((b >> 16) & 1u)) >> 16);
}
__device__ __forceinline__ float bf2f(unsigned short h) {
    return __uint_as_float(((unsigned)h) << 16);
}
__device__ __forceinline__ void async16(const void* g, void* l) {
    __builtin_amdgcn_global_load_lds((const __attribute__((address_space(1))) void*)g,
                                     (__attribute__((address_space(3))) void*)l, 16, 0, 0);
}

// chunk-major element address (in shorts): buf[b][rblk][kb][row128][8]

// ---- Pass 0: convert x -> chunk-major split-bf16; also zero den (no memset)
__global__ __launch_bounds__(256) void conv_k(
    const float* __restrict__ x,
    unsigned short* __restrict__ hiT, unsigned short* __restrict__ loT,
    float* __restrict__ den)          // den_row[4][HW] ++ den_col[4][HW]
{
    int b = blockIdx.z, l0 = blockIdx.x * 64, d0 = blockIdx.y * 64;
    __shared__ float t[64][65];
    int tid = threadIdx.x;
    if (blockIdx.y == 0 && blockIdx.z == 0) {         // 58 blocks zero 28800 floats
        int base = blockIdx.x * 512;
        for (int i = tid; i < 512; i += 256) {
            int g = base + i;
            if (g < 28800) den[g] = 0.f;
        }
    }
#pragma unroll
    for (int r = 0; r < 4; r++) {
        int idx = tid + 256 * r;              // 1024 float4 slots
        int d = idx >> 4, lq = idx & 15;
        int l = l0 + lq * 4;
        const float* src = x + ((size_t)b * 128 + d0 + d) * HW;
        float4 v;
        if (l + 3 < HW) v = *(const float4*)(src + l);
        else {
            v.x = (l     < HW) ? src[l]     : 0.f;
            v.y = (l + 1 < HW) ? src[l + 1] : 0.f;
            v.z = (l + 2 < HW) ? src[l + 2] : 0.f;
            v.w = (l + 3 < HW) ? src[l + 3] : 0.f;
        }
        t[lq * 4 + 0][d] = v.x; t[lq * 4 + 1][d] = v.y;
        t[lq * 4 + 2][d] = v.z; t[lq * 4 + 3][d] = v.w;
    }
    __syncthreads();
    const int rblk = l0 >> 7;
#pragma unroll
    for (int r = 0; r < 2; r++) {
        int idx = tid + 256 * r;              // 512 chunks of 8 bf16
        int l = idx & 63, dq = idx >> 6;      // row-inner -> coalesced stores
        unsigned hp[4], lp[4];
#pragma unroll
        for (int j = 0; j < 4; j++) {
            float f0 = t[l][dq * 8 + 2 * j], f1 = t[l][dq * 8 + 2 * j + 1];
            unsigned short h0 = f2bf(f0), h1 = f2bf(f1);
            unsigned short g0 = f2bf(f0 - bf2f(h0)), g1 = f2bf(f1 - bf2f(h1));
            hp[j] = (unsigned)h0 | ((unsigned)h1 << 16);
            lp[j] = (unsigned)g0 | ((unsigned)g1 << 16);
        }
        size_t o = ((size_t)(b * 29 + rblk) * 16 + (d0 >> 3) + dq) * 1024
                 + (size_t)((l0 + l) & 127) * 8;
        *(uint4*)(hiT + o) = make_uint4(hp[0], hp[1], hp[2], hp[3]);
        *(uint4*)(loT + o) = make_uint4(lp[0], lp[1], lp[2], lp[3]);
    }
}

// ---- Pass A: double-buffered LDS-staged 32x32x16 GEMM; stats epilogue ------
__global__ __launch_bounds__(256) void gemm_mfma_k(
    const unsigned short* __restrict__ hiT, const unsigned short* __restrict__ loT,
    float* __restrict__ den_row, float* __restrict__ den_col,
    float* __restrict__ maxvt)
{
    const int batch = blockIdx.z, bx = blockIdx.x, by = blockIdx.y;
    __shared__ __align__(16) unsigned short stage[2][4][4][128][8];  // 65536 B

    const int tid = threadIdx.x;
    const int lane = tid & 63, w = tid >> 6;
    const int wr = w >> 1, wc = w & 1;
    const int l31 = lane & 31, h = lane >> 5;

    const unsigned short* psrc = (w == 0) ? hiT : (w == 1) ? loT : (w == 2) ? hiT : loT;
    const int bsel = (w < 2) ? batch : batch + 4;
    const int rblk = (w < 2) ? by : bx;
    const size_t cbase = ((size_t)(bsel * 29 + rblk) * 16) * 1024;

    auto issue = [&](int buf, int k0) {
#pragma unroll
        for (int i = 0; i < 8; i++) {
            int kb = i >> 1, half = i & 1;
            const unsigned short* g = psrc + cbase + (size_t)((k0 >> 3) + kb) * 1024
                                    + (half << 9) + lane * 8;
            async16(g, &stage[buf][w][kb][half << 6][0]);
        }
    };

    float16v acc[2][2];
#pragma unroll
    for (int i = 0; i < 2; i++)
#pragma unroll
        for (int j = 0; j < 2; j++) acc[i][j] = (float16v)(0.f);

    issue(0, 0);
#pragma unroll
    for (int it = 0; it < 4; it++) {
        if (it < 3) {
            issue((it + 1) & 1, (it + 1) * 32);
            __asm__ __volatile__("s_waitcnt vmcnt(8)" ::: "memory");
        } else {
            __asm__ __volatile__("s_waitcnt vmcnt(0)" ::: "memory");
        }
        __asm__ __volatile__("s_barrier" ::: "memory");   // cur buffer ready (all waves)
        const int cb = it & 1;
#pragma unroll
        for (int j = 0; j < 2; j++) {
            int kb = j * 2 + h;
            short8 ah[2], al[2], bh[2], bl[2];
#pragma unroll
            for (int t = 0; t < 2; t++) {
                ah[t] = *(const short8*)&stage[cb][0][kb][wr * 64 + t * 32 + l31][0];
                al[t] = *(const short8*)&stage[cb][1][kb][wr * 64 + t * 32 + l31][0];
                bh[t] = *(const short8*)&stage[cb][2][kb][wc * 64 + t * 32 + l31][0];
                bl[t] = *(const short8*)&stage[cb][3][kb][wc * 64 + t * 32 + l31][0];
            }
#pragma unroll
            for (int mt = 0; mt < 2; mt++)
#pragma unroll
                for (int nt = 0; nt < 2; nt++) {
                    acc[mt][nt] = __builtin_amdgcn_mfma_f32_32x32x16_bf16(ah[mt], bh[nt], acc[mt][nt], 0, 0, 0);
                    acc[mt][nt] = __builtin_amdgcn_mfma_f32_32x32x16_bf16(ah[mt], bl[nt], acc[mt][nt], 0, 0, 0);
                    acc[mt][nt] = __builtin_amdgcn_mfma_f32_32x32x16_bf16(al[mt], bh[nt], acc[mt][nt], 0, 0, 0);
                }
        }
        __asm__ __volatile__("s_barrier" ::: "memory");   // reads done before next overwrite
    }
    __syncthreads();

    // ---- epilogue: per-wave LDS transpose (reuses stage; wave-private) ----
    const float scale = 0.078125f;   // 1/(128*0.1)
    float* T = ((float*)stage) + w * (64 * 34);
    const bool interior = (bx < 28) && (by < 28);
    const int col0 = bx * 128 + wc * 64 + l31;
    const bool c0v = interior || (col0 < HW);
    const bool c1v = interior || (col0 + 32 < HW);
    float cs0 = 0.f, cs1 = 0.f;

#pragma unroll
    for (int mt = 0; mt < 2; mt++)
#pragma unroll
        for (int reg = 0; reg < 16; reg++) {
            float v0 = acc[mt][0][reg] * scale;
            float v1 = acc[mt][1][reg] * scale;
            float e0 = c0v ? __expf(v0) : 0.f;
            float e1 = c1v ? __expf(v1) : 0.f;
            int row64 = mt * 32 + (reg & 3) + 8 * (reg >> 2) + 4 * h;
            bool rv = interior || (by * 128 + wr * 64 + row64 < HW);
            if (rv) { cs0 += e0; cs1 += e1; }
            T[row64 * 34 + l31] = e0 + e1;
        }
    __asm__ __volatile__("s_waitcnt lgkmcnt(0)" ::: "memory");
    float rsum = 0.f;
#pragma unroll
    for (int i = 0; i < 16; i++) {
        float2 p = *(const float2*)&T[lane * 34 + 2 * i];
        rsum += p.x + p.y;
    }
    __asm__ __volatile__("s_waitcnt lgkmcnt(0)" ::: "memory");
    const int lrow = by * 128 + wr * 64 + lane;
    const bool rowv = interior || (lrow < HW);
    if (rowv) atomicAdd(&den_row[(size_t)batch * HW + lrow], rsum);

#pragma unroll
    for (int mt = 0; mt < 2; mt++)
#pragma unroll
        for (int reg = 0; reg < 16; reg++) {
            float m0 = c0v ? acc[mt][0][reg] : -3.4e38f;
            float m1 = c1v ? acc[mt][1][reg] : -3.4e38f;
            int row64 = mt * 32 + (reg & 3) + 8 * (reg >> 2) + 4 * h;
            T[row64 * 34 + l31] = fmaxf(m0, m1) * scale;
        }
    __asm__ __volatile__("s_waitcnt lgkmcnt(0)" ::: "memory");
    float rmax = -3.4e38f;
#pragma unroll
    for (int i = 0; i < 16; i++) {
        float2 p = *(const float2*)&T[lane * 34 + 2 * i];
        rmax = fmaxf(rmax, fmaxf(p.x, p.y));
    }
    const int ct = bx * 2 + wc;
    if (rowv) maxvt[((size_t)batch * NT + ct) * PADR + lrow] = rmax;

    cs0 += __shfl_xor(cs0, 32);
    cs1 += __shfl_xor(cs1, 32);
    if (h == 0) {
        if (c0v) atomicAdd(&den_col[(size_t)batch * HW + col0], cs0);
        if (c1v) atomicAdd(&den_col[(size_t)batch * HW + col0 + 32], cs1);
    }
}

// ---- Pass B: per-(tile,batch) block: redundant tau + pairs + recompute -----
__global__ __launch_bounds__(256) void recollect_k(
    const unsigned short* __restrict__ hiT, const unsigned short* __restrict__ loT,
    const float* __restrict__ den_row, const float* __restrict__ den_col,
    const float* __restrict__ maxvt,
    uint2* __restrict__ cand, int* __restrict__ cnt58)
{
    const int t = blockIdx.x, batch = blockIdx.y;
    const int tid = threadIdx.x;
    __shared__ float lnrS[HW];            // 14400 B
    __shared__ float maxlncS[NT];
    __shared__ float lncS[64];
    __shared__ float mnlS, tauS;
    __shared__ unsigned uS[HW];           // keys, then pair rows (14400 B)
    __shared__ unsigned hist[4096];       // hist, then candS=uint2[2048] (16384 B)
    __shared__ unsigned hpc[256];
    __shared__ int b1S, c1S, b2S, lcntS, pcS, ccS;
    __shared__ unsigned bestS;
    __shared__ unsigned listS[1024];

    for (int i = tid; i < HW; i += 256)
        lnrS[i] = __logf(den_row[(size_t)batch * HW + i]);
    if (tid < NT) {                       // per-tile max of lnc
        float mx = -3.4e38f;
        int s0 = tid * 64, s1 = s0 + 64; if (s1 > HW) s1 = HW;
        for (int s = s0; s < s1; s++) mx = fmaxf(mx, __logf(den_col[(size_t)batch * HW + s]));
        maxlncS[tid] = (s0 < HW) ? mx : 1e30f;
    }
    if (tid < 64) {                       // own tile lnc + min
        int c = t * 64 + tid;
        float lc = (c < HW) ? __logf(den_col[(size_t)batch * HW + c]) : 1e30f;
        lncS[tid] = lc;
        float mn = lc;
#pragma unroll
        for (int off = 1; off < 64; off <<= 1) mn = fminf(mn, __shfl_xor(mn, off));
        if (tid == 0) mnlS = mn;
    }
    for (int i = tid; i < 4096; i += 256) hist[i] = 0u;
    if (tid == 0) { lcntS = 0; bestS = 0u; pcS = 0; ccS = 0; }
    __syncthreads();

    // keylb per row + level-1 hist
    for (int r = tid; r < HW; r += 256) {
        float best = -3.4e38f;
        for (int tt = 0; tt < NT; tt++)
            best = fmaxf(best, 2.0f * maxvt[((size_t)batch * NT + tt) * PADR + r] - maxlncS[tt]);
        unsigned k = monof(best - lnrS[r]);
        uS[r] = k;
        atomicAdd(&hist[k >> 20], 1u);
    }
    __syncthreads();
    { unsigned s = 0; for (int j = 0; j < 16; j++) s += hist[tid * 16 + j]; hpc[tid] = s; }
    __syncthreads();
    if (tid == 0) {
        unsigned cum = 0; int cs_ = 255;
        for (; cs_ > 0; cs_--) { if (cum + hpc[cs_] >= (unsigned)KSEL) break; cum += hpc[cs_]; }
        int bb = cs_ * 16 + 15;
        for (; bb > cs_ * 16; bb--) { if (cum + hist[bb] >= (unsigned)KSEL) break; cum += hist[bb]; }
        b1S = bb; c1S = (int)cum;
    }
    __syncthreads();
    int b1 = b1S;
    for (int i = tid; i < 4096; i += 256) hist[i] = 0u;
    __syncthreads();
    for (int i = tid; i < HW; i += 256) {
        unsigned k = uS[i];
        if ((int)(k >> 20) == b1) atomicAdd(&hist[(k >> 8) & 4095], 1u);
    }
    __syncthreads();
    { unsigned s = 0; for (int j = 0; j < 16; j++) s += hist[tid * 16 + j]; hpc[tid] = s; }
    __syncthreads();
    if (tid == 0) {
        unsigned cum = (unsigned)c1S; int cs_ = 255;
        for (; cs_ > 0; cs_--) { if (cum + hpc[cs_] >= (unsigned)KSEL) break; cum += hpc[cs_]; }
        int bb = cs_ * 16 + 15;
        for (; bb > cs_ * 16; bb--) { if (cum + hist[bb] >= (unsigned)KSEL) break; cum += hist[bb]; }
        b2S = bb;
    }
    __syncthreads();
    int b2 = b2S;
    for (int i = tid; i < HW; i += 256) {
        unsigned k = uS[i]; int hb = (int)(k >> 20);
        if (hb > b1 || (hb == b1 && (int)((k >> 8) & 4095) >= b2)) {
            int p = atomicAdd(&lcntS, 1);
            if (p < 1024) listS[p] = k;
        }
    }
    __syncthreads();
    int L = lcntS; if (L > 1024) L = 1024;
    for (int i = tid; i < L; i += 256) {
        unsigned e = listS[i]; int c = 0;
        for (int j = 0; j < L; j++) c += (listS[j] >= e) ? 1 : 0;
        if (c >= KSEL) atomicMax(&bestS, e);
    }
    __syncthreads();
    if (tid == 0) tauS = unmonof(bestS) - 3e-4f;   // slack: cross-kernel drift
    __syncthreads();

    // pairs for this tile (uS reused as row list)
    const float tv = tauS;
    const float tvm = tv - 3e-4f;
    const float mnl = mnlS;
    const float* mv = maxvt + ((size_t)batch * NT + t) * PADR;
    for (int r = tid; r < HW; r += 256) {
        float bnd = 2.0f * mv[r] - lnrS[r] - mnl;
        if (bnd >= tvm) {
            int p = atomicAdd(&pcS, 1);
            ((int*)uS)[p] = r;
        }
    }
    __syncthreads();
    const int pc = pcS;
    uint2* candS = (uint2*)hist;          // hist dead; 2048 entries

    if (pc > 0) {
        const int* pr = (const int*)uS;
        const int lane = tid & 63, w = tid >> 6;
        const int m = lane & 15, q = lane >> 4;
        const float scale = 0.078125f;
        const size_t abase = (size_t)batch * PADR * 128;
        const size_t bbase = (size_t)(batch + 4) * PADR * 128;

        for (int g = w; g * 16 < pc; g += 4) {
            int pi = g * 16 + m;
            int rowv = (pi < pc) ? pr[pi] : HW;       // pad rows are zeros
            float ldrv = (pi < pc) ? lnrS[rowv] : 0.f;
            size_t arow = abase + ((size_t)(rowv >> 7) * 16) * 1024 + (size_t)(rowv & 127) * 8;

            float4v acc[4];
#pragma unroll
            for (int i = 0; i < 4; i++) acc[i] = (float4v){0.f, 0.f, 0.f, 0.f};
#pragma unroll
            for (int k0 = 0; k0 < 128; k0 += 32) {
                int kb = (k0 >> 3) + q;
                short8 ah = *(const short8*)(hiT + arow + (size_t)kb * 1024);
                short8 al = *(const short8*)(loT + arow + (size_t)kb * 1024);
#pragma unroll
                for (int nt = 0; nt < 4; nt++) {
                    int c = t * 64 + nt * 16 + m;
                    size_t brow = bbase + ((size_t)(c >> 7) * 16 + kb) * 1024 + (size_t)(c & 127) * 8;
                    short8 bh = *(const short8*)(hiT + brow);
                    short8 bl = *(const short8*)(loT + brow);
                    acc[nt] = __builtin_amdgcn_mfma_f32_16x16x32_bf16(ah, bh, acc[nt], 0, 0, 0);
                    acc[nt] = __builtin_amdgcn_mfma_f32_16x16x32_bf16(ah, bl, acc[nt], 0, 0, 0);
                    acc[nt] = __builtin_amdgcn_mfma_f32_16x16x32_bf16(al, bh, acc[nt], 0, 0, 0);
                }
            }
#pragma unroll
            for (int nt = 0; nt < 4; nt++) {
                int c = t * 64 + nt * 16 + m;
                if (c >= HW) continue;
                float ldc = lncS[nt * 16 + m];
#pragma unroll
                for (int r = 0; r < 4; r++) {
                    int ri = q * 4 + r;
                    if (g * 16 + ri >= pc) continue;
                    int rowo = __shfl(rowv, ri);
                    float ldro = __shfl(ldrv, ri);
                    float v = acc[nt][r] * scale;
                    float tt2 = 2.0f * v - ldro - ldc;
                    if (tt2 >= tv) {
                        int p = atomicAdd(&ccS, 1);
                        if (p < SLICE)
                            candS[p] = make_uint2(monof(tt2), (unsigned)(rowo * HW + c));
                    }
                }
            }
        }
    }
    __syncthreads();
    int cc = ccS; if (cc > SLICE) cc = SLICE;
    uint2* slice = cand + ((size_t)batch * NT + t) * SLICE;
    for (int i = tid; i < cc; i += 256) slice[i] = candS[i];
    if (tid == 0) cnt58[batch * NT + t] = cc;
}

// ---- Pass C: fused select + elementwise output -----------------------------
__global__ __launch_bounds__(256) void final_k(
    const float* __restrict__ x, const float* __restrict__ W,
    const float* __restrict__ bias,
    const uint2* __restrict__ cand, const int* __restrict__ cnt58,
    float* __restrict__ out)
{
    const int bd = blockIdx.x;
    const int b8 = bd >> 7, d = bd & 127;
    const int batch = b8 & 3;
    const bool useQ = (b8 < 4);
    const int tid = threadIdx.x;
    const int lane = tid & 63, w = tid >> 6;

    __shared__ U64 lk[6144];
    __shared__ int offS[NT + 1];
    __shared__ int topiS[KSEL];
    __shared__ float cxS[KSEL], cyS[KSEL];
    __shared__ float redC[4], redX[4], redY[4];
    __shared__ float cstS, sxS, syS;

    if (tid == 0) {
        int o = 0;
        for (int t = 0; t < NT; t++) {
            offS[t] = o;
            o += cnt58[batch * NT + t];
            if (o > 6144) o = 6144;
        }
        offS[NT] = o;
    }
    __syncthreads();
    const int M = offS[NT];
    for (int t = 0; t < NT; t++) {
        int o0 = offS[t], n = offS[t + 1] - o0;
        const uint2* slice = cand + ((size_t)batch * NT + t) * SLICE;
        for (int i = tid; i < n; i += 256) {
            uint2 e = slice[i];
            lk[o0 + i] = ((U64)e.x << 32) | (unsigned)(~e.y);
        }
    }
    __syncthreads();
    for (int i = tid; i < M; i += 256) {
        U64 e = lk[i]; int r = 0;
        for (int j = 0; j < M; j++) r += (lk[j] > e) ? 1 : 0;   // unique keys
        if (r < KSEL) topiS[r] = (int)(~(unsigned)(e & 0xffffffffu));
    }
    __syncthreads();
    if (tid < KSEL) {
        int idx = topiS[tid];
        int qq = idx / HW, rr = idx - qq * HW;
        int sel = useQ ? qq : rr;
        cxS[tid] = (float)(sel % 60) / 60.0f;
        cyS[tid] = (float)(sel / 60) / 60.0f;
    }
    __syncthreads();
    float pC = 0.f, pX = 0.f, pY = 0.f;
    if (tid < KSEL) {
        float wx = W[d * 200 + 2 * tid], wy = W[d * 200 + 2 * tid + 1];
        pC = cxS[tid] * wx + cyS[tid] * wy;
        pX = wx; pY = wy;
    }
#pragma unroll
    for (int off = 1; off < 64; off <<= 1) {
        pC += __shfl_xor(pC, off);
        pX += __shfl_xor(pX, off);
        pY += __shfl_xor(pY, off);
    }
    if (lane == 0) { redC[w] = pC; redX[w] = pX; redY[w] = pY; }
    __syncthreads();
    if (tid == 0) {
        cstS = bias[d] - (redC[0] + redC[1] + redC[2] + redC[3]);
        sxS  = redX[0] + redX[1] + redX[2] + redX[3];
        syS  = redY[0] + redY[1] + redY[2] + redY[3];
    }
    __syncthreads();
    const float cst = cstS, sx = sxS, sy = syS;
    const float4* xin = (const float4*)(x + (size_t)bd * HW);
    float4* o4 = (float4*)(out + (size_t)bd * HW);
    for (int f = tid; f < NF4; f += 256) {
        float4 v = xin[f];
        int p0 = f * 4;
        float gy = (float)(p0 / 60) / 60.0f;
        float gxb = (float)(p0 % 60);
        float add = cst + gy * sy;
        v.x += add + ((gxb       ) / 60.0f) * sx;
        v.y += add + ((gxb + 1.f) / 60.0f) * sx;
        v.z += add + ((gxb + 2.f) / 60.0f) * sx;
        v.w += add + ((gxb + 3.f) / 60.0f) * sx;
        o4[f] = v;
    }
}

extern "C" void kernel_launch(void* const* d_in, const int* in_sizes, int n_in,
                              void* d_out, int out_size, void* d_ws, size_t ws_size,
                              hipStream_t stream)
{
    const float* x    = (const float*)d_in[0];
    const float* W    = (const float*)d_in[1];
    const float* bias = (const float*)d_in[2];
    float* out = (float*)d_out;

    char* ws = (char*)d_ws;
    float*    den     = (float*)(ws + 0);          // den_row[4][HW] ++ den_col[4][HW]
    float*    den_row = den;
    float*    den_col = (float*)(ws + 57600);      // -> 115200
    int*      cnt58   = (int*)  (ws + 115200);     // 928 -> 116128
    uint2*    cand    = (uint2*)(ws + 116224);     // 4*58*2048*8 = 3801088 -> 3917312
    float*    maxvt   = (float*)(ws + 3917312);    // 3444736 -> 7362048
    unsigned short* hiT = (unsigned short*)(ws + 7362048);   // 7602176 -> 14964224
    unsigned short* loT = (unsigned short*)(ws + 14964224);  // 7602176 -> 22566400

    conv_k     <<<dim3(58, 2, 8),  256, 0, stream>>>(x, hiT, loT, den);
    gemm_mfma_k<<<dim3(29, 29, 4), 256, 0, stream>>>(hiT, loT, den_row, den_col, maxvt);
    recollect_k<<<dim3(NT, 4),     256, 0, stream>>>(hiT, loT, den_row, den_col, maxvt, cand, cnt58);
    final_k    <<<dim3(1024),      256, 0, stream>>>(x, W, bias, cand, cnt58, out);
}

// Round 10
// 257.222 us; speedup vs baseline: 1.3601x; 1.3601x over previous
//
#include <hip/hip_runtime.h>

#define HW 3600
#define PADR 3712            // 29*128 padded rows
#define NF4 900
#define CAP 16384
#define KSEL 100
#define NT 58                // 64-col tiles
typedef unsigned long long U64;

using short8   = __attribute__((ext_vector_type(8))) short;
using float4v  = __attribute__((ext_vector_type(4))) float;
using float16v = __attribute__((ext_vector_type(16))) float;

__device__ __forceinline__ unsigned monof(float f) {
    unsigned b = __float_as_uint(f);
    return (b & 0x80000000u) ? ~b : (b | 0x80000000u);
}
__device__ __forceinline__ float unmonof(unsigned m) {
    return __uint_as_float((m & 0x80000000u) ? (m ^ 0x80000000u) : ~m);
}
__device__ __forceinline__ unsigned short f2bf(float f) {   // RNE
    unsigned b = __float_as_uint(f);
    return (unsigned short)((b + 0x7FFFu + ((b >> 16) & 1u)) >> 16);
}
__device__ __forceinline__ float bf2f(unsigned short h) {
    return __uint_as_float(((unsigned)h) << 16);
}
__device__ __forceinline__ void async16(const void* g, void* l) {
    __builtin_amdgcn_global_load_lds((const __attribute__((address_space(1))) void*)g,
                                     (__attribute__((address_space(3))) void*)l, 16, 0, 0);
}

// chunk-major element address (in shorts): buf[b][rblk][kb][row128][8]

// ---- Pass 0: convert x -> chunk-major split-bf16; zero den+cnt (no memset) -
__global__ __launch_bounds__(256) void conv_k(
    const float* __restrict__ x,
    unsigned short* __restrict__ hiT, unsigned short* __restrict__ loT,
    unsigned* __restrict__ zero_region)   // den(28800 f) ++ cnt(4) ++ tau(4)
{
    int b = blockIdx.z, l0 = blockIdx.x * 64, d0 = blockIdx.y * 64;
    __shared__ float t[64][65];
    int tid = threadIdx.x;
    if (blockIdx.y == 0 && blockIdx.z == 0) {
        int base = blockIdx.x * 512;
        for (int i = tid; i < 512; i += 256) {
            int g = base + i;
            if (g < 28808) zero_region[g] = 0u;
        }
    }
#pragma unroll
    for (int r = 0; r < 4; r++) {
        int idx = tid + 256 * r;              // 1024 float4 slots
        int d = idx >> 4, lq = idx & 15;
        int l = l0 + lq * 4;
        const float* src = x + ((size_t)b * 128 + d0 + d) * HW;
        float4 v;
        if (l + 3 < HW) v = *(const float4*)(src + l);
        else {
            v.x = (l     < HW) ? src[l]     : 0.f;
            v.y = (l + 1 < HW) ? src[l + 1] : 0.f;
            v.z = (l + 2 < HW) ? src[l + 2] : 0.f;
            v.w = (l + 3 < HW) ? src[l + 3] : 0.f;
        }
        t[lq * 4 + 0][d] = v.x; t[lq * 4 + 1][d] = v.y;
        t[lq * 4 + 2][d] = v.z; t[lq * 4 + 3][d] = v.w;
    }
    __syncthreads();
    const int rblk = l0 >> 7;
#pragma unroll
    for (int r = 0; r < 2; r++) {
        int idx = tid + 256 * r;              // 512 chunks of 8 bf16
        int l = idx & 63, dq = idx >> 6;      // row-inner -> coalesced stores
        unsigned hp[4], lp[4];
#pragma unroll
        for (int j = 0; j < 4; j++) {
            float f0 = t[l][dq * 8 + 2 * j], f1 = t[l][dq * 8 + 2 * j + 1];
            unsigned short h0 = f2bf(f0), h1 = f2bf(f1);
            unsigned short g0 = f2bf(f0 - bf2f(h0)), g1 = f2bf(f1 - bf2f(h1));
            hp[j] = (unsigned)h0 | ((unsigned)h1 << 16);
            lp[j] = (unsigned)g0 | ((unsigned)g1 << 16);
        }
        size_t o = ((size_t)(b * 29 + rblk) * 16 + (d0 >> 3) + dq) * 1024
                 + (size_t)((l0 + l) & 127) * 8;
        *(uint4*)(hiT + o) = make_uint4(hp[0], hp[1], hp[2], hp[3]);
        *(uint4*)(loT + o) = make_uint4(lp[0], lp[1], lp[2], lp[3]);
    }
}

// ---- Pass A: 512-thread 8-wave LDS-staged 32x32x16 GEMM; stats epilogue ----
// Each wave computes 64 rows x 32 cols (2 vertical 32x32 MFMA tiles -> 32 AGPR).
__global__ __launch_bounds__(512) void gemm_mfma_k(
    const unsigned short* __restrict__ hiT, const unsigned short* __restrict__ loT,
    float* __restrict__ den_row, float* __restrict__ den_col,
    float* __restrict__ maxvt)
{
    const int batch = blockIdx.z, bx = blockIdx.x, by = blockIdx.y;
    __shared__ __align__(16) union SU {
        unsigned short st[4][4][128][8];   // 32768 B staging
        float T[8448];                     // 33792 B epilogue transpose (8 waves x 32x33)
    } u;
    __shared__ float rsB[128];
    __shared__ float csB[128];
    __shared__ unsigned mxB[2][128];

    const int tid = threadIdx.x;
    const int lane = tid & 63, w = tid >> 6;          // 8 waves
    const int l31 = lane & 31, h = lane >> 5;
    const int p = w >> 1, halfr = w & 1;              // staging role
    const int rg = w >> 2, cg = w & 3;                // compute role

    const unsigned NEGM = monof(-3.4e38f);
    if (tid < 128) { rsB[tid] = 0.f; csB[tid] = 0.f; }
    if (tid < 256) mxB[tid >> 7][tid & 127] = NEGM;

    const unsigned short* psrc = (p == 0) ? hiT : (p == 1) ? loT : (p == 2) ? hiT : loT;
    const int bsel = (p < 2) ? batch : batch + 4;
    const int rblk = (p < 2) ? by : bx;
    const size_t cbase = ((size_t)(bsel * 29 + rblk) * 16) * 1024;

    float16v acc[2];
    acc[0] = (float16v)(0.f);
    acc[1] = (float16v)(0.f);

    for (int k0 = 0; k0 < 128; k0 += 32) {
#pragma unroll
        for (int kb = 0; kb < 4; kb++) {
            const unsigned short* g = psrc + cbase + (size_t)((k0 >> 3) + kb) * 1024
                                    + (halfr << 9) + lane * 8;
            async16(g, &u.st[p][kb][halfr << 6][0]);
        }
        __syncthreads();
#pragma unroll
        for (int j = 0; j < 2; j++) {
            int kb = j * 2 + h;
            short8 ah[2], al[2], bh, bl;
            ah[0] = *(const short8*)&u.st[0][kb][rg * 64 + l31][0];
            ah[1] = *(const short8*)&u.st[0][kb][rg * 64 + 32 + l31][0];
            al[0] = *(const short8*)&u.st[1][kb][rg * 64 + l31][0];
            al[1] = *(const short8*)&u.st[1][kb][rg * 64 + 32 + l31][0];
            bh    = *(const short8*)&u.st[2][kb][cg * 32 + l31][0];
            bl    = *(const short8*)&u.st[3][kb][cg * 32 + l31][0];
#pragma unroll
            for (int mt = 0; mt < 2; mt++) {
                acc[mt] = __builtin_amdgcn_mfma_f32_32x32x16_bf16(ah[mt], bh, acc[mt], 0, 0, 0);
                acc[mt] = __builtin_amdgcn_mfma_f32_32x32x16_bf16(ah[mt], bl, acc[mt], 0, 0, 0);
                acc[mt] = __builtin_amdgcn_mfma_f32_32x32x16_bf16(al[mt], bh, acc[mt], 0, 0, 0);
            }
        }
        __syncthreads();
    }

    // ---- epilogue: per-wave 32x33 LDS transpose (u.T, wave-private region) --
    // C/D: col = cg*32 + l31, row = rg*64 + mt*32 + (reg&3)+8*(reg>>2)+4*h
    const float scale = 0.078125f;   // 1/(128*0.1)
    float* T = u.T + w * (32 * 33);
    const bool interior = (bx < 28) && (by < 28);
    const int col0 = bx * 128 + cg * 32 + l31;
    const bool cv = interior || (col0 < HW);
    float cs = 0.f;

#pragma unroll
    for (int mt = 0; mt < 2; mt++) {
        // ---- row sums ----
#pragma unroll
        for (int reg = 0; reg < 16; reg++) {
            float v = acc[mt][reg] * scale;
            float e = cv ? __expf(v) : 0.f;
            int rloc = (reg & 3) + 8 * (reg >> 2) + 4 * h;
            bool rv = interior || (by * 128 + rg * 64 + mt * 32 + rloc < HW);
            if (rv) cs += e;
            T[rloc * 33 + l31] = e;
        }
        __asm__ __volatile__("s_waitcnt lgkmcnt(0)" ::: "memory");
        {
            float ps = 0.f;
#pragma unroll
            for (int i = 0; i < 16; i++) ps += T[l31 * 33 + h * 16 + i];
            ps += __shfl_xor(ps, 32);
            if (h == 0) atomicAdd(&rsB[rg * 64 + mt * 32 + l31], ps);
        }
        __asm__ __volatile__("s_waitcnt lgkmcnt(0)" ::: "memory");
        // ---- row max ----
#pragma unroll
        for (int reg = 0; reg < 16; reg++) {
            float v = acc[mt][reg] * scale;
            int rloc = (reg & 3) + 8 * (reg >> 2) + 4 * h;
            T[rloc * 33 + l31] = cv ? v : -3.4e38f;
        }
        __asm__ __volatile__("s_waitcnt lgkmcnt(0)" ::: "memory");
        {
            float pm = -3.4e38f;
#pragma unroll
            for (int i = 0; i < 16; i++) pm = fmaxf(pm, T[l31 * 33 + h * 16 + i]);
            pm = fmaxf(pm, __shfl_xor(pm, 32));
            if (h == 0) atomicMax(&mxB[cg >> 1][rg * 64 + mt * 32 + l31], monof(pm));
        }
        __asm__ __volatile__("s_waitcnt lgkmcnt(0)" ::: "memory");
    }
    // col sums: h pair covers complementary rows of the same column
    cs += __shfl_xor(cs, 32);
    if (h == 0) atomicAdd(&csB[cg * 32 + l31], cs);
    __syncthreads();

    if (tid < 128) {
        int l = by * 128 + tid;
        if (l < HW) atomicAdd(&den_row[(size_t)batch * HW + l], rsB[tid]);
        int s = bx * 128 + tid;
        if (s < HW) atomicAdd(&den_col[(size_t)batch * HW + s], csB[tid]);
    }
    if (tid < 256) {
        int tile = tid >> 7, row = tid & 127;
        int l = by * 128 + row;
        if (l < HW)
            maxvt[((size_t)batch * NT + bx * 2 + tile) * PADR + l] =
                unmonof(mxB[tile][row]);
    }
}

// ---- Pass B: merged stat+tau: per-row champion lower bound -> exact 100th --
__global__ __launch_bounds__(256) void tau_k(
    const float* __restrict__ den_row, const float* __restrict__ den_col,
    const float* __restrict__ maxvt, float* __restrict__ tau)
{
    const int b = blockIdx.z, tid = threadIdx.x;
    __shared__ float lncS[HW];
    __shared__ float mlsS[NT];
    __shared__ unsigned keyS[HW];
    __shared__ unsigned hist[4096];
    __shared__ unsigned hpc[256];
    __shared__ int b1S, c1S, b2S, lcnt;
    __shared__ unsigned bestS;
    __shared__ unsigned list[1024];

    for (int i = tid; i < HW; i += 256)
        lncS[i] = __logf(den_col[(size_t)b * HW + i]);
    for (int i = tid; i < 4096; i += 256) hist[i] = 0u;
    if (tid == 0) { lcnt = 0; bestS = 0u; }
    __syncthreads();
    if (tid < NT) {
        float mx = -3.4e38f;
        int s0 = tid * 64, s1 = s0 + 64; if (s1 > HW) s1 = HW;
        for (int s = s0; s < s1; s++) mx = fmaxf(mx, lncS[s]);
        mlsS[tid] = (s0 < HW) ? mx : 1e30f;
    }
    __syncthreads();

    const float* mvb = maxvt + (size_t)b * NT * PADR;
    for (int r = tid; r < HW; r += 256) {
        float b0 = -3.4e38f, b1_ = -3.4e38f;
#pragma unroll 4
        for (int tt = 0; tt < 56; tt += 2) {
            b0  = fmaxf(b0,  2.0f * mvb[(size_t)tt * PADR + r]       - mlsS[tt]);
            b1_ = fmaxf(b1_, 2.0f * mvb[(size_t)(tt + 1) * PADR + r] - mlsS[tt + 1]);
        }
        b0  = fmaxf(b0,  2.0f * mvb[(size_t)56 * PADR + r] - mlsS[56]);
        b1_ = fmaxf(b1_, 2.0f * mvb[(size_t)57 * PADR + r] - mlsS[57]);
        float best = fmaxf(b0, b1_) - __logf(den_row[(size_t)b * HW + r]);
        unsigned k = monof(best);
        keyS[r] = k;
        atomicAdd(&hist[k >> 20], 1u);
    }
    __syncthreads();
    { unsigned s = 0; for (int j = 0; j < 16; j++) s += hist[tid * 16 + j]; hpc[tid] = s; }
    __syncthreads();
    if (tid == 0) {
        unsigned cum = 0; int cs_ = 255;
        for (; cs_ > 0; cs_--) { if (cum + hpc[cs_] >= (unsigned)KSEL) break; cum += hpc[cs_]; }
        int bb = cs_ * 16 + 15;
        for (; bb > cs_ * 16; bb--) { if (cum + hist[bb] >= (unsigned)KSEL) break; cum += hist[bb]; }
        b1S = bb; c1S = (int)cum;
    }
    __syncthreads();
    int b1 = b1S;
    for (int i = tid; i < 4096; i += 256) hist[i] = 0u;
    __syncthreads();
    for (int i = tid; i < HW; i += 256) {
        unsigned k = keyS[i];
        if ((int)(k >> 20) == b1) atomicAdd(&hist[(k >> 8) & 4095], 1u);
    }
    __syncthreads();
    { unsigned s = 0; for (int j = 0; j < 16; j++) s += hist[tid * 16 + j]; hpc[tid] = s; }
    __syncthreads();
    if (tid == 0) {
        unsigned cum = (unsigned)c1S; int cs_ = 255;
        for (; cs_ > 0; cs_--) { if (cum + hpc[cs_] >= (unsigned)KSEL) break; cum += hpc[cs_]; }
        int bb = cs_ * 16 + 15;
        for (; bb > cs_ * 16; bb--) { if (cum + hist[bb] >= (unsigned)KSEL) break; cum += hist[bb]; }
        b2S = bb;
    }
    __syncthreads();
    int b2 = b2S;
    for (int i = tid; i < HW; i += 256) {
        unsigned k = keyS[i]; int hb = (int)(k >> 20);
        if (hb > b1 || (hb == b1 && (int)((k >> 8) & 4095) >= b2)) {
            int p = atomicAdd(&lcnt, 1);
            if (p < 1024) list[p] = k;
        }
    }
    __syncthreads();
    int L = lcnt; if (L > 1024) L = 1024;
    for (int i = tid; i < L; i += 256) {
        unsigned e = list[i]; int c = 0;
        for (int j = 0; j < L; j++) c += (list[j] >= e) ? 1 : 0;
        if (c >= KSEL) atomicMax(&bestS, e);
    }
    __syncthreads();
    if (tid == 0) tau[b] = unmonof(bestS) - 3e-4f;   // slack: cross-kernel drift
}

// ---- Pass C: pairs + recompute + collect (R7 structure) --------------------
__global__ __launch_bounds__(256) void recollect_k(
    const unsigned short* __restrict__ hiT, const unsigned short* __restrict__ loT,
    const float* __restrict__ den_row, const float* __restrict__ den_col,
    const float* __restrict__ maxvt, const float* __restrict__ tau,
    uint2* __restrict__ cand, int* __restrict__ cnt)
{
    const int t = blockIdx.x, batch = blockIdx.y;
    const int tid = threadIdx.x;
    __shared__ float lnrS[HW];
    __shared__ float lncS[64];
    __shared__ int prS[2048];
    __shared__ int pcS;
    __shared__ float mnlS;

    if (tid < 64) {
        int c = t * 64 + tid;
        float lc = (c < HW) ? __logf(den_col[(size_t)batch * HW + c]) : 1e30f;
        lncS[tid] = lc;
        float mn = lc;
#pragma unroll
        for (int off = 1; off < 64; off <<= 1) mn = fminf(mn, __shfl_xor(mn, off));
        if (tid == 0) mnlS = mn;
    }
    for (int r = tid; r < HW; r += 256)
        lnrS[r] = __logf(den_row[(size_t)batch * HW + r]);
    if (tid == 0) pcS = 0;
    __syncthreads();

    const float tv = tau[batch];
    const float tvm = tv - 3e-4f;
    const float mnl = mnlS;
    const float* mv = maxvt + ((size_t)batch * NT + t) * PADR;
    for (int r = tid; r < HW; r += 256) {
        float bnd = 2.0f * mv[r] - lnrS[r] - mnl;
        if (bnd >= tvm) {
            int p = atomicAdd(&pcS, 1);
            if (p < 2048) prS[p] = r;
        }
    }
    __syncthreads();
    int pc = pcS; if (pc > 2048) pc = 2048;
    if (pc == 0) return;

    const int lane = tid & 63, w = tid >> 6;
    const int m = lane & 15, q = lane >> 4;
    const float scale = 0.078125f;
    const size_t abase = (size_t)batch * PADR * 128;
    const size_t bbase = (size_t)(batch + 4) * PADR * 128;

    for (int g = w; g * 16 < pc; g += 4) {
        int pi = g * 16 + m;
        int rowv = (pi < pc) ? prS[pi] : HW;       // pad rows are zeros
        float ldrv = (pi < pc) ? lnrS[rowv] : 0.f;
        size_t arow = abase + ((size_t)(rowv >> 7) * 16) * 1024 + (size_t)(rowv & 127) * 8;

        float4v acc[4];
#pragma unroll
        for (int i = 0; i < 4; i++) acc[i] = (float4v){0.f, 0.f, 0.f, 0.f};
#pragma unroll
        for (int k0 = 0; k0 < 128; k0 += 32) {
            int kb = (k0 >> 3) + q;
            short8 ah = *(const short8*)(hiT + arow + (size_t)kb * 1024);
            short8 al = *(const short8*)(loT + arow + (size_t)kb * 1024);
#pragma unroll
            for (int nt = 0; nt < 4; nt++) {
                int c = t * 64 + nt * 16 + m;
                size_t brow = bbase + ((size_t)(c >> 7) * 16 + kb) * 1024 + (size_t)(c & 127) * 8;
                short8 bh = *(const short8*)(hiT + brow);
                short8 bl = *(const short8*)(loT + brow);
                acc[nt] = __builtin_amdgcn_mfma_f32_16x16x32_bf16(ah, bh, acc[nt], 0, 0, 0);
                acc[nt] = __builtin_amdgcn_mfma_f32_16x16x32_bf16(ah, bl, acc[nt], 0, 0, 0);
                acc[nt] = __builtin_amdgcn_mfma_f32_16x16x32_bf16(al, bh, acc[nt], 0, 0, 0);
            }
        }
#pragma unroll
        for (int nt = 0; nt < 4; nt++) {
            int c = t * 64 + nt * 16 + m;
            if (c >= HW) continue;
            float ldc = lncS[nt * 16 + m];
#pragma unroll
            for (int r = 0; r < 4; r++) {
                int ri = q * 4 + r;
                if (g * 16 + ri >= pc) continue;
                int rowo = __shfl(rowv, ri);
                float ldro = __shfl(ldrv, ri);
                float v = acc[nt][r] * scale;
                float tt2 = 2.0f * v - ldro - ldc;
                if (tt2 >= tv) {
                    int p = atomicAdd(&cnt[batch], 1);
                    if (p < CAP)
                        cand[(size_t)batch * CAP + p] =
                            make_uint2(monof(tt2), (unsigned)(rowo * HW + c));
                }
            }
        }
    }
}

// ---- Pass D: fused exact select + elementwise output -----------------------
__global__ __launch_bounds__(256) void final_k(
    const float* __restrict__ x, const float* __restrict__ W,
    const float* __restrict__ bias,
    const uint2* __restrict__ cand, const int* __restrict__ cnt,
    float* __restrict__ out)
{
    const int bd = blockIdx.x;
    const int b8 = bd >> 7, d = bd & 127;
    const int batch = b8 & 3;
    const bool useQ = (b8 < 4);
    const int tid = threadIdx.x;
    const int lane = tid & 63, w = tid >> 6;
    const uint2* cb = cand + (size_t)batch * CAP;

    __shared__ U64 lk[6144];
    __shared__ int topiS[KSEL];
    __shared__ float cxS[KSEL], cyS[KSEL];
    __shared__ float redC[4], redX[4], redY[4];
    __shared__ float cstS, sxS, syS;

    int M = cnt[batch]; if (M > CAP) M = CAP;
    const bool useL = (M <= 6144);
    if (useL)
        for (int i = tid; i < M; i += 256) {
            uint2 e = cb[i];
            lk[i] = ((U64)e.x << 32) | (unsigned)(~e.y);
        }
    __syncthreads();
    for (int i = tid; i < M; i += 256) {
        U64 e;
        if (useL) e = lk[i];
        else { uint2 tt = cb[i]; e = ((U64)tt.x << 32) | (unsigned)(~tt.y); }
        int r = 0;
        for (int j = 0; j < M; j++) {
            U64 o;
            if (useL) o = lk[j];
            else { uint2 tt = cb[j]; o = ((U64)tt.x << 32) | (unsigned)(~tt.y); }
            r += (o > e) ? 1 : 0;
        }
        if (r < KSEL) topiS[r] = (int)(~(unsigned)(e & 0xffffffffu));
    }
    __syncthreads();
    if (tid < KSEL) {
        int idx = topiS[tid];
        int qq = idx / HW, rr = idx - qq * HW;
        int sel = useQ ? qq : rr;
        cxS[tid] = (float)(sel % 60) / 60.0f;
        cyS[tid] = (float)(sel / 60) / 60.0f;
    }
    __syncthreads();
    float pC = 0.f, pX = 0.f, pY = 0.f;
    if (tid < KSEL) {
        float wx = W[d * 200 + 2 * tid], wy = W[d * 200 + 2 * tid + 1];
        pC = cxS[tid] * wx + cyS[tid] * wy;
        pX = wx; pY = wy;
    }
#pragma unroll
    for (int off = 1; off < 64; off <<= 1) {
        pC += __shfl_xor(pC, off);
        pX += __shfl_xor(pX, off);
        pY += __shfl_xor(pY, off);
    }
    if (lane == 0) { redC[w] = pC; redX[w] = pX; redY[w] = pY; }
    __syncthreads();
    if (tid == 0) {
        cstS = bias[d] - (redC[0] + redC[1] + redC[2] + redC[3]);
        sxS  = redX[0] + redX[1] + redX[2] + redX[3];
        syS  = redY[0] + redY[1] + redY[2] + redY[3];
    }
    __syncthreads();
    const float cst = cstS, sx = sxS, sy = syS;
    const float4* xin = (const float4*)(x + (size_t)bd * HW);
    float4* o4 = (float4*)(out + (size_t)bd * HW);
    for (int f = tid; f < NF4; f += 256) {
        float4 v = xin[f];
        int p0 = f * 4;
        float gy = (float)(p0 / 60) / 60.0f;
        float gxb = (float)(p0 % 60);
        float add = cst + gy * sy;
        v.x += add + ((gxb       ) / 60.0f) * sx;
        v.y += add + ((gxb + 1.f) / 60.0f) * sx;
        v.z += add + ((gxb + 2.f) / 60.0f) * sx;
        v.w += add + ((gxb + 3.f) / 60.0f) * sx;
        o4[f] = v;
    }
}

extern "C" void kernel_launch(void* const* d_in, const int* in_sizes, int n_in,
                              void* d_out, int out_size, void* d_ws, size_t ws_size,
                              hipStream_t stream)
{
    const float* x    = (const float*)d_in[0];
    const float* W    = (const float*)d_in[1];
    const float* bias = (const float*)d_in[2];
    float* out = (float*)d_out;

    char* ws = (char*)d_ws;
    float*    den_row = (float*)(ws + 0);          // 57600
    float*    den_col = (float*)(ws + 57600);      // -> 115200
    int*      cnt     = (int*)  (ws + 115200);     // 16
    float*    tau     = (float*)(ws + 115216);     // 16 -> 115232 (conv zeroes 0..115232)
    uint2*    cand    = (uint2*)(ws + 115264);     // 4*16384*8 = 524288 -> 639552
    float*    maxvt   = (float*)(ws + 639552);     // 3444736 -> 4084288
    unsigned short* hiT = (unsigned short*)(ws + 4084288);   // 7602176 -> 11686464
    unsigned short* loT = (unsigned short*)(ws + 11686464);  // 7602176 -> 19288640

    conv_k     <<<dim3(58, 2, 8),  256, 0, stream>>>(x, hiT, loT, (unsigned*)ws);
    gemm_mfma_k<<<dim3(29, 29, 4), 512, 0, stream>>>(hiT, loT, den_row, den_col, maxvt);
    tau_k      <<<dim3(1, 1, 4),   256, 0, stream>>>(den_row, den_col, maxvt, tau);
    recollect_k<<<dim3(NT, 4),     256, 0, stream>>>(hiT, loT, den_row, den_col, maxvt, tau, cand, cnt);
    final_k    <<<dim3(1024),      256, 0, stream>>>(x, W, bias, cand, cnt, out);
}

// Round 11
// 223.667 us; speedup vs baseline: 1.5641x; 1.1500x over previous
//
#include <hip/hip_runtime.h>

#define HW 3600
#define PADR 3712            // 29*128 padded rows
#define NF4 900
#define CAP 16384
#define KSEL 100
#define NT 58                // 64-col tiles
typedef unsigned long long U64;

using short8   = __attribute__((ext_vector_type(8))) short;
using float4v  = __attribute__((ext_vector_type(4))) float;
using float16v = __attribute__((ext_vector_type(16))) float;

__device__ __forceinline__ unsigned monof(float f) {
    unsigned b = __float_as_uint(f);
    return (b & 0x80000000u) ? ~b : (b | 0x80000000u);
}
__device__ __forceinline__ float unmonof(unsigned m) {
    return __uint_as_float((m & 0x80000000u) ? (m ^ 0x80000000u) : ~m);
}
__device__ __forceinline__ unsigned short f2bf(float f) {   // RNE
    unsigned b = __float_as_uint(f);
    return (unsigned short)((b + 0x7FFFu + ((b >> 16) & 1u)) >> 16);
}
__device__ __forceinline__ float bf2f(unsigned short h) {
    return __uint_as_float(((unsigned)h) << 16);
}
__device__ __forceinline__ void async16(const void* g, void* l) {
    __builtin_amdgcn_global_load_lds((const __attribute__((address_space(1))) void*)g,
                                     (__attribute__((address_space(3))) void*)l, 16, 0, 0);
}

// chunk-major element address (in shorts): buf[b][rblk][kb][row128][8]

// ---- Pass 0: convert x -> chunk-major split-bf16; zero den+cnt (no memset) -
__global__ __launch_bounds__(256) void conv_k(
    const float* __restrict__ x,
    unsigned short* __restrict__ hiT, unsigned short* __restrict__ loT,
    unsigned* __restrict__ zero_region)   // den(28800 f) ++ cnt(4) ++ tau(4)
{
    int b = blockIdx.z, l0 = blockIdx.x * 64, d0 = blockIdx.y * 64;
    __shared__ float t[64][65];
    int tid = threadIdx.x;
    if (blockIdx.y == 0 && blockIdx.z == 0) {
        int base = blockIdx.x * 512;
        for (int i = tid; i < 512; i += 256) {
            int g = base + i;
            if (g < 28808) zero_region[g] = 0u;
        }
    }
#pragma unroll
    for (int r = 0; r < 4; r++) {
        int idx = tid + 256 * r;              // 1024 float4 slots
        int d = idx >> 4, lq = idx & 15;
        int l = l0 + lq * 4;
        const float* src = x + ((size_t)b * 128 + d0 + d) * HW;
        float4 v;
        if (l + 3 < HW) v = *(const float4*)(src + l);
        else {
            v.x = (l     < HW) ? src[l]     : 0.f;
            v.y = (l + 1 < HW) ? src[l + 1] : 0.f;
            v.z = (l + 2 < HW) ? src[l + 2] : 0.f;
            v.w = (l + 3 < HW) ? src[l + 3] : 0.f;
        }
        t[lq * 4 + 0][d] = v.x; t[lq * 4 + 1][d] = v.y;
        t[lq * 4 + 2][d] = v.z; t[lq * 4 + 3][d] = v.w;
    }
    __syncthreads();
    const int rblk = l0 >> 7;
#pragma unroll
    for (int r = 0; r < 2; r++) {
        int idx = tid + 256 * r;              // 512 chunks of 8 bf16
        int l = idx & 63, dq = idx >> 6;      // row-inner -> coalesced stores
        unsigned hp[4], lp[4];
#pragma unroll
        for (int j = 0; j < 4; j++) {
            float f0 = t[l][dq * 8 + 2 * j], f1 = t[l][dq * 8 + 2 * j + 1];
            unsigned short h0 = f2bf(f0), h1 = f2bf(f1);
            unsigned short g0 = f2bf(f0 - bf2f(h0)), g1 = f2bf(f1 - bf2f(h1));
            hp[j] = (unsigned)h0 | ((unsigned)h1 << 16);
            lp[j] = (unsigned)g0 | ((unsigned)g1 << 16);
        }
        size_t o = ((size_t)(b * 29 + rblk) * 16 + (d0 >> 3) + dq) * 1024
                 + (size_t)((l0 + l) & 127) * 8;
        *(uint4*)(hiT + o) = make_uint4(hp[0], hp[1], hp[2], hp[3]);
        *(uint4*)(loT + o) = make_uint4(lp[0], lp[1], lp[2], lp[3]);
    }
}

// ---- Pass A: 512-thread 8-wave LDS-staged 32x32x16 GEMM; stats epilogue ----
// Each wave computes 64 rows x 32 cols (2 vertical 32x32 MFMA tiles -> 32 AGPR).
__global__ __launch_bounds__(512) void gemm_mfma_k(
    const unsigned short* __restrict__ hiT, const unsigned short* __restrict__ loT,
    float* __restrict__ den_row, float* __restrict__ den_col,
    float* __restrict__ maxvt)
{
    const int batch = blockIdx.z, bx = blockIdx.x, by = blockIdx.y;
    __shared__ __align__(16) union SU {
        unsigned short st[4][4][128][8];   // 32768 B staging
        float T[8448];                     // 33792 B epilogue transpose (8 waves x 32x33)
    } u;
    __shared__ float rsB[128];
    __shared__ float csB[128];
    __shared__ unsigned mxB[2][128];

    const int tid = threadIdx.x;
    const int lane = tid & 63, w = tid >> 6;          // 8 waves
    const int l31 = lane & 31, h = lane >> 5;
    const int p = w >> 1, halfr = w & 1;              // staging role
    const int rg = w >> 2, cg = w & 3;                // compute role

    const unsigned NEGM = monof(-3.4e38f);
    if (tid < 128) { rsB[tid] = 0.f; csB[tid] = 0.f; }
    if (tid < 256) mxB[tid >> 7][tid & 127] = NEGM;

    const unsigned short* psrc = (p == 0) ? hiT : (p == 1) ? loT : (p == 2) ? hiT : loT;
    const int bsel = (p < 2) ? batch : batch + 4;
    const int rblk = (p < 2) ? by : bx;
    const size_t cbase = ((size_t)(bsel * 29 + rblk) * 16) * 1024;

    float16v acc[2];
    acc[0] = (float16v)(0.f);
    acc[1] = (float16v)(0.f);

    for (int k0 = 0; k0 < 128; k0 += 32) {
#pragma unroll
        for (int kb = 0; kb < 4; kb++) {
            const unsigned short* g = psrc + cbase + (size_t)((k0 >> 3) + kb) * 1024
                                    + (halfr << 9) + lane * 8;
            async16(g, &u.st[p][kb][halfr << 6][0]);
        }
        __syncthreads();
#pragma unroll
        for (int j = 0; j < 2; j++) {
            int kb = j * 2 + h;
            short8 ah[2], al[2], bh, bl;
            ah[0] = *(const short8*)&u.st[0][kb][rg * 64 + l31][0];
            ah[1] = *(const short8*)&u.st[0][kb][rg * 64 + 32 + l31][0];
            al[0] = *(const short8*)&u.st[1][kb][rg * 64 + l31][0];
            al[1] = *(const short8*)&u.st[1][kb][rg * 64 + 32 + l31][0];
            bh    = *(const short8*)&u.st[2][kb][cg * 32 + l31][0];
            bl    = *(const short8*)&u.st[3][kb][cg * 32 + l31][0];
#pragma unroll
            for (int mt = 0; mt < 2; mt++) {
                acc[mt] = __builtin_amdgcn_mfma_f32_32x32x16_bf16(ah[mt], bh, acc[mt], 0, 0, 0);
                acc[mt] = __builtin_amdgcn_mfma_f32_32x32x16_bf16(ah[mt], bl, acc[mt], 0, 0, 0);
                acc[mt] = __builtin_amdgcn_mfma_f32_32x32x16_bf16(al[mt], bh, acc[mt], 0, 0, 0);
            }
        }
        __syncthreads();
    }

    // ---- epilogue: per-wave 32x33 LDS transpose (u.T, wave-private region) --
    // C/D: col = cg*32 + l31, row = rg*64 + mt*32 + (reg&3)+8*(reg>>2)+4*h
    const float scale = 0.078125f;   // 1/(128*0.1)
    float* T = u.T + w * (32 * 33);
    const bool interior = (bx < 28) && (by < 28);
    const int col0 = bx * 128 + cg * 32 + l31;
    const bool cv = interior || (col0 < HW);
    float cs = 0.f;

#pragma unroll
    for (int mt = 0; mt < 2; mt++) {
        // ---- row sums ----
#pragma unroll
        for (int reg = 0; reg < 16; reg++) {
            float v = acc[mt][reg] * scale;
            float e = cv ? __expf(v) : 0.f;
            int rloc = (reg & 3) + 8 * (reg >> 2) + 4 * h;
            bool rv = interior || (by * 128 + rg * 64 + mt * 32 + rloc < HW);
            if (rv) cs += e;
            T[rloc * 33 + l31] = e;
        }
        __asm__ __volatile__("s_waitcnt lgkmcnt(0)" ::: "memory");
        {
            float ps = 0.f;
#pragma unroll
            for (int i = 0; i < 16; i++) ps += T[l31 * 33 + h * 16 + i];
            ps += __shfl_xor(ps, 32);
            if (h == 0) atomicAdd(&rsB[rg * 64 + mt * 32 + l31], ps);
        }
        __asm__ __volatile__("s_waitcnt lgkmcnt(0)" ::: "memory");
        // ---- row max ----
#pragma unroll
        for (int reg = 0; reg < 16; reg++) {
            float v = acc[mt][reg] * scale;
            int rloc = (reg & 3) + 8 * (reg >> 2) + 4 * h;
            T[rloc * 33 + l31] = cv ? v : -3.4e38f;
        }
        __asm__ __volatile__("s_waitcnt lgkmcnt(0)" ::: "memory");
        {
            float pm = -3.4e38f;
#pragma unroll
            for (int i = 0; i < 16; i++) pm = fmaxf(pm, T[l31 * 33 + h * 16 + i]);
            pm = fmaxf(pm, __shfl_xor(pm, 32));
            if (h == 0) atomicMax(&mxB[cg >> 1][rg * 64 + mt * 32 + l31], monof(pm));
        }
        __asm__ __volatile__("s_waitcnt lgkmcnt(0)" ::: "memory");
    }
    // col sums: h pair covers complementary rows of the same column
    cs += __shfl_xor(cs, 32);
    if (h == 0) atomicAdd(&csB[cg * 32 + l31], cs);
    __syncthreads();

    if (tid < 128) {
        int l = by * 128 + tid;
        if (l < HW) atomicAdd(&den_row[(size_t)batch * HW + l], rsB[tid]);
        int s = bx * 128 + tid;
        if (s < HW) atomicAdd(&den_col[(size_t)batch * HW + s], csB[tid]);
    }
    if (tid < 256) {
        int tile = tid >> 7, row = tid & 127;
        int l = by * 128 + row;
        if (l < HW)
            maxvt[((size_t)batch * NT + bx * 2 + tile) * PADR + l] =
                unmonof(mxB[tile][row]);
    }
}

// ---- Pass B1: WIDE keylb: per-row champion-key lower bound -----------------
// keylb[j] = max_t (2*maxvt[t][j] - maxlnc[t]) - ln(den_row[j])
__global__ __launch_bounds__(256) void stat_k(
    const float* __restrict__ den_row, const float* __restrict__ den_col,
    const float* __restrict__ maxvt, float* __restrict__ keylb)
{
    const int b = blockIdx.z, tid = threadIdx.x;
    __shared__ float lncS[HW];
    __shared__ float mlsS[NT];
    for (int i = tid; i < HW; i += 256)
        lncS[i] = __logf(den_col[(size_t)b * HW + i]);
    __syncthreads();
    if (tid < NT) {
        float mx = -3.4e38f;
        int s0 = tid * 64, s1 = s0 + 64; if (s1 > HW) s1 = HW;
        for (int s = s0; s < s1; s++) mx = fmaxf(mx, lncS[s]);
        mlsS[tid] = (s0 < HW) ? mx : 1e30f;
    }
    __syncthreads();
    int j = blockIdx.x * 240 + tid;
    if (tid < 240 && j < HW) {
        const float* mvb = maxvt + (size_t)b * NT * PADR;
        float b0 = -3.4e38f, b1_ = -3.4e38f;
#pragma unroll 4
        for (int tt = 0; tt < 58; tt += 2) {
            b0  = fmaxf(b0,  2.0f * mvb[(size_t)tt * PADR + j]       - mlsS[tt]);
            b1_ = fmaxf(b1_, 2.0f * mvb[(size_t)(tt + 1) * PADR + j] - mlsS[tt + 1]);
        }
        keylb[(size_t)b * HW + j] = fmaxf(b0, b1_) - __logf(den_row[(size_t)b * HW + j]);
    }
}

// ---- Pass B2: exact 100th-largest keylb via 2-level hist + rank -> tau -----
__global__ __launch_bounds__(256) void tau_k(
    const float* __restrict__ keylb, float* __restrict__ tau)
{
    const int b = blockIdx.z, tid = threadIdx.x;
    __shared__ unsigned keyS[HW];
    __shared__ unsigned hist[4096];
    __shared__ unsigned hpc[256];
    __shared__ int b1S, c1S, b2S, lcnt;
    __shared__ unsigned bestS;
    __shared__ unsigned list[1024];

    for (int i = tid; i < 4096; i += 256) hist[i] = 0u;
    if (tid == 0) { lcnt = 0; bestS = 0u; }
    __syncthreads();
    for (int i = tid; i < HW; i += 256) {
        unsigned k = monof(keylb[(size_t)b * HW + i]);
        keyS[i] = k;
        atomicAdd(&hist[k >> 20], 1u);
    }
    __syncthreads();
    { unsigned s = 0; for (int j = 0; j < 16; j++) s += hist[tid * 16 + j]; hpc[tid] = s; }
    __syncthreads();
    if (tid == 0) {
        unsigned cum = 0; int cs_ = 255;
        for (; cs_ > 0; cs_--) { if (cum + hpc[cs_] >= (unsigned)KSEL) break; cum += hpc[cs_]; }
        int bb = cs_ * 16 + 15;
        for (; bb > cs_ * 16; bb--) { if (cum + hist[bb] >= (unsigned)KSEL) break; cum += hist[bb]; }
        b1S = bb; c1S = (int)cum;
    }
    __syncthreads();
    int b1 = b1S;
    for (int i = tid; i < 4096; i += 256) hist[i] = 0u;
    __syncthreads();
    for (int i = tid; i < HW; i += 256) {
        unsigned k = keyS[i];
        if ((int)(k >> 20) == b1) atomicAdd(&hist[(k >> 8) & 4095], 1u);
    }
    __syncthreads();
    { unsigned s = 0; for (int j = 0; j < 16; j++) s += hist[tid * 16 + j]; hpc[tid] = s; }
    __syncthreads();
    if (tid == 0) {
        unsigned cum = (unsigned)c1S; int cs_ = 255;
        for (; cs_ > 0; cs_--) { if (cum + hpc[cs_] >= (unsigned)KSEL) break; cum += hpc[cs_]; }
        int bb = cs_ * 16 + 15;
        for (; bb > cs_ * 16; bb--) { if (cum + hist[bb] >= (unsigned)KSEL) break; cum += hist[bb]; }
        b2S = bb;
    }
    __syncthreads();
    int b2 = b2S;
    for (int i = tid; i < HW; i += 256) {
        unsigned k = keyS[i]; int hb = (int)(k >> 20);
        if (hb > b1 || (hb == b1 && (int)((k >> 8) & 4095) >= b2)) {
            int p = atomicAdd(&lcnt, 1);
            if (p < 1024) list[p] = k;
        }
    }
    __syncthreads();
    int L = lcnt; if (L > 1024) L = 1024;
    for (int i = tid; i < L; i += 256) {
        unsigned e = list[i]; int c = 0;
        for (int j = 0; j < L; j++) c += (list[j] >= e) ? 1 : 0;
        if (c >= KSEL) atomicMax(&bestS, e);
    }
    __syncthreads();
    if (tid == 0) tau[b] = unmonof(bestS) - 3e-4f;   // slack: cross-kernel drift
}

// ---- Pass C: pairs + recompute + collect (R7 structure) --------------------
__global__ __launch_bounds__(256) void recollect_k(
    const unsigned short* __restrict__ hiT, const unsigned short* __restrict__ loT,
    const float* __restrict__ den_row, const float* __restrict__ den_col,
    const float* __restrict__ maxvt, const float* __restrict__ tau,
    uint2* __restrict__ cand, int* __restrict__ cnt)
{
    const int t = blockIdx.x, batch = blockIdx.y;
    const int tid = threadIdx.x;
    __shared__ float lnrS[HW];
    __shared__ float lncS[64];
    __shared__ int prS[2048];
    __shared__ int pcS;
    __shared__ float mnlS;

    if (tid < 64) {
        int c = t * 64 + tid;
        float lc = (c < HW) ? __logf(den_col[(size_t)batch * HW + c]) : 1e30f;
        lncS[tid] = lc;
        float mn = lc;
#pragma unroll
        for (int off = 1; off < 64; off <<= 1) mn = fminf(mn, __shfl_xor(mn, off));
        if (tid == 0) mnlS = mn;
    }
    for (int r = tid; r < HW; r += 256)
        lnrS[r] = __logf(den_row[(size_t)batch * HW + r]);
    if (tid == 0) pcS = 0;
    __syncthreads();

    const float tv = tau[batch];
    const float tvm = tv - 3e-4f;
    const float mnl = mnlS;
    const float* mv = maxvt + ((size_t)batch * NT + t) * PADR;
    for (int r = tid; r < HW; r += 256) {
        float bnd = 2.0f * mv[r] - lnrS[r] - mnl;
        if (bnd >= tvm) {
            int p = atomicAdd(&pcS, 1);
            if (p < 2048) prS[p] = r;
        }
    }
    __syncthreads();
    int pc = pcS; if (pc > 2048) pc = 2048;
    if (pc == 0) return;

    const int lane = tid & 63, w = tid >> 6;
    const int m = lane & 15, q = lane >> 4;
    const float scale = 0.078125f;
    const size_t abase = (size_t)batch * PADR * 128;
    const size_t bbase = (size_t)(batch + 4) * PADR * 128;

    for (int g = w; g * 16 < pc; g += 4) {
        int pi = g * 16 + m;
        int rowv = (pi < pc) ? prS[pi] : HW;       // pad rows are zeros
        float ldrv = (pi < pc) ? lnrS[rowv] : 0.f;
        size_t arow = abase + ((size_t)(rowv >> 7) * 16) * 1024 + (size_t)(rowv & 127) * 8;

        float4v acc[4];
#pragma unroll
        for (int i = 0; i < 4; i++) acc[i] = (float4v){0.f, 0.f, 0.f, 0.f};
#pragma unroll
        for (int k0 = 0; k0 < 128; k0 += 32) {
            int kb = (k0 >> 3) + q;
            short8 ah = *(const short8*)(hiT + arow + (size_t)kb * 1024);
            short8 al = *(const short8*)(loT + arow + (size_t)kb * 1024);
#pragma unroll
            for (int nt = 0; nt < 4; nt++) {
                int c = t * 64 + nt * 16 + m;
                size_t brow = bbase + ((size_t)(c >> 7) * 16 + kb) * 1024 + (size_t)(c & 127) * 8;
                short8 bh = *(const short8*)(hiT + brow);
                short8 bl = *(const short8*)(loT + brow);
                acc[nt] = __builtin_amdgcn_mfma_f32_16x16x32_bf16(ah, bh, acc[nt], 0, 0, 0);
                acc[nt] = __builtin_amdgcn_mfma_f32_16x16x32_bf16(ah, bl, acc[nt], 0, 0, 0);
                acc[nt] = __builtin_amdgcn_mfma_f32_16x16x32_bf16(al, bh, acc[nt], 0, 0, 0);
            }
        }
#pragma unroll
        for (int nt = 0; nt < 4; nt++) {
            int c = t * 64 + nt * 16 + m;
            if (c >= HW) continue;
            float ldc = lncS[nt * 16 + m];
#pragma unroll
            for (int r = 0; r < 4; r++) {
                int ri = q * 4 + r;
                if (g * 16 + ri >= pc) continue;
                int rowo = __shfl(rowv, ri);
                float ldro = __shfl(ldrv, ri);
                float v = acc[nt][r] * scale;
                float tt2 = 2.0f * v - ldro - ldc;
                if (tt2 >= tv) {
                    int p = atomicAdd(&cnt[batch], 1);
                    if (p < CAP)
                        cand[(size_t)batch * CAP + p] =
                            make_uint2(monof(tt2), (unsigned)(rowo * HW + c));
                }
            }
        }
    }
}

// ---- Pass D: fused exact select + elementwise output -----------------------
__global__ __launch_bounds__(256) void final_k(
    const float* __restrict__ x, const float* __restrict__ W,
    const float* __restrict__ bias,
    const uint2* __restrict__ cand, const int* __restrict__ cnt,
    float* __restrict__ out)
{
    const int bd = blockIdx.x;
    const int b8 = bd >> 7, d = bd & 127;
    const int batch = b8 & 3;
    const bool useQ = (b8 < 4);
    const int tid = threadIdx.x;
    const int lane = tid & 63, w = tid >> 6;
    const uint2* cb = cand + (size_t)batch * CAP;

    __shared__ U64 lk[6144];
    __shared__ int topiS[KSEL];
    __shared__ float cxS[KSEL], cyS[KSEL];
    __shared__ float redC[4], redX[4], redY[4];
    __shared__ float cstS, sxS, syS;

    int M = cnt[batch]; if (M > CAP) M = CAP;
    const bool useL = (M <= 6144);
    if (useL)
        for (int i = tid; i < M; i += 256) {
            uint2 e = cb[i];
            lk[i] = ((U64)e.x << 32) | (unsigned)(~e.y);
        }
    __syncthreads();
    for (int i = tid; i < M; i += 256) {
        U64 e;
        if (useL) e = lk[i];
        else { uint2 tt = cb[i]; e = ((U64)tt.x << 32) | (unsigned)(~tt.y); }
        int r = 0;
        for (int j = 0; j < M; j++) {
            U64 o;
            if (useL) o = lk[j];
            else { uint2 tt = cb[j]; o = ((U64)tt.x << 32) | (unsigned)(~tt.y); }
            r += (o > e) ? 1 : 0;
        }
        if (r < KSEL) topiS[r] = (int)(~(unsigned)(e & 0xffffffffu));
    }
    __syncthreads();
    if (tid < KSEL) {
        int idx = topiS[tid];
        int qq = idx / HW, rr = idx - qq * HW;
        int sel = useQ ? qq : rr;
        cxS[tid] = (float)(sel % 60) / 60.0f;
        cyS[tid] = (float)(sel / 60) / 60.0f;
    }
    __syncthreads();
    float pC = 0.f, pX = 0.f, pY = 0.f;
    if (tid < KSEL) {
        float wx = W[d * 200 + 2 * tid], wy = W[d * 200 + 2 * tid + 1];
        pC = cxS[tid] * wx + cyS[tid] * wy;
        pX = wx; pY = wy;
    }
#pragma unroll
    for (int off = 1; off < 64; off <<= 1) {
        pC += __shfl_xor(pC, off);
        pX += __shfl_xor(pX, off);
        pY += __shfl_xor(pY, off);
    }
    if (lane == 0) { redC[w] = pC; redX[w] = pX; redY[w] = pY; }
    __syncthreads();
    if (tid == 0) {
        cstS = bias[d] - (redC[0] + redC[1] + redC[2] + redC[3]);
        sxS  = redX[0] + redX[1] + redX[2] + redX[3];
        syS  = redY[0] + redY[1] + redY[2] + redY[3];
    }
    __syncthreads();
    const float cst = cstS, sx = sxS, sy = syS;
    const float4* xin = (const float4*)(x + (size_t)bd * HW);
    float4* o4 = (float4*)(out + (size_t)bd * HW);
    for (int f = tid; f < NF4; f += 256) {
        float4 v = xin[f];
        int p0 = f * 4;
        float gy = (float)(p0 / 60) / 60.0f;
        float gxb = (float)(p0 % 60);
        float add = cst + gy * sy;
        v.x += add + ((gxb       ) / 60.0f) * sx;
        v.y += add + ((gxb + 1.f) / 60.0f) * sx;
        v.z += add + ((gxb + 2.f) / 60.0f) * sx;
        v.w += add + ((gxb + 3.f) / 60.0f) * sx;
        o4[f] = v;
    }
}

extern "C" void kernel_launch(void* const* d_in, const int* in_sizes, int n_in,
                              void* d_out, int out_size, void* d_ws, size_t ws_size,
                              hipStream_t stream)
{
    const float* x    = (const float*)d_in[0];
    const float* W    = (const float*)d_in[1];
    const float* bias = (const float*)d_in[2];
    float* out = (float*)d_out;

    char* ws = (char*)d_ws;
    float*    den_row = (float*)(ws + 0);          // 57600
    float*    den_col = (float*)(ws + 57600);      // -> 115200
    int*      cnt     = (int*)  (ws + 115200);     // 16
    float*    tau     = (float*)(ws + 115216);     // 16 -> 115232 (conv zeroes 0..115232)
    float*    keylb   = (float*)(ws + 115264);     // 57600 -> 172864
    uint2*    cand    = (uint2*)(ws + 172864);     // 524288 -> 697152
    float*    maxvt   = (float*)(ws + 697152);     // 3444736 -> 4141888
    unsigned short* hiT = (unsigned short*)(ws + 4141888);   // 7602176 -> 11744064
    unsigned short* loT = (unsigned short*)(ws + 11744064);  // 7602176 -> 19346240

    conv_k     <<<dim3(58, 2, 8),  256, 0, stream>>>(x, hiT, loT, (unsigned*)ws);
    gemm_mfma_k<<<dim3(29, 29, 4), 512, 0, stream>>>(hiT, loT, den_row, den_col, maxvt);
    stat_k     <<<dim3(15, 1, 4),  256, 0, stream>>>(den_row, den_col, maxvt, keylb);
    tau_k      <<<dim3(1, 1, 4),   256, 0, stream>>>(keylb, tau);
    recollect_k<<<dim3(NT, 4),     256, 0, stream>>>(hiT, loT, den_row, den_col, maxvt, tau, cand, cnt);
    final_k    <<<dim3(1024),      256, 0, stream>>>(x, W, bias, cand, cnt, out);
}